// Round 7
// baseline (1988.141 us; speedup 1.0000x reference)
//
#include <hip/hip_runtime.h>

// SimpleRNN: h_{t+1} = tanh(h_t @ H^T + x_t @ U + b); out = h_T @ A^T + c
// T=512 B=2048 IN=28 HID=198 OUT=10, all fp32.
//
// R7: persistent kernel, grid=256 (1 block/CU), BB=8 batch rows/block,
// 1024 threads = 16 waves = 4 waves/SIMD (R6 lesson: 2/SIMD is latency-dead).
// Waves 0-12: compute ONE 16-col N-tile each, 7 H-slots, 14 MFMAs in 4
//   chains (depth <=4). xu (=x@U+b) is read from LDS and added post-fold.
// Waves 13,14: xu-producers: compute xu[t+1] = x[t+1]@U + b via 2 MFMAs/tile
//   (M-packed x hi/lo), fold in-wave, write to lds_xu[(t+1)&1] in
//   reader-lane layout (lane-indexed 16B rows, conflict-free).
// Wave 15: idle (barriers only).
// This rebalances MFMA across SIMDs (max 56/step vs 64) and frees compute-
// wave registers (U-frags gone) for the 4-chain accumulator split.
//
// hi/lo-packed M: A rows 0-7 = h_hi, rows 8-15 = h_lo; 2 passes (Bhi,Blo),
// fold C[r]+C[r+8] via v_permlane32_swap -> exact (hi+lo)*(Bhi+Blo).
// tanh = 1 - 2*rcp(exp2(2*log2e*x)+1). One __syncthreads per step.

#define T_STEPS 512
#define BATCH   2048
#define IN_DIM  28
#define HID     198
#define OUT_DIM 10
#define BB      8    // batch rows per block
#define KT      7    // H k-tiles of 32 (224 >= 198)
#define NCW     13   // compute waves / N-tiles

typedef __attribute__((ext_vector_type(8))) __bf16 bf16x8;
typedef __attribute__((ext_vector_type(4))) float  floatx4;

__device__ __forceinline__ floatx4 mfma16(bf16x8 a, bf16x8 b, floatx4 c) {
    return __builtin_amdgcn_mfma_f32_16x16x32_bf16(a, b, c, 0, 0, 0);
}

// tanh(x) = 1 - 2/(exp(2x)+1); exp2-based, saturates via IEEE inf/0.
__device__ __forceinline__ float fast_tanh(float x) {
    float e = __builtin_amdgcn_exp2f(x * 2.885390081777926357f); // exp(2x)
    float r = __builtin_amdgcn_rcpf(e + 1.0f);
    return __builtin_fmaf(-2.0f, r, 1.0f);
}

// s[lane] + s[lane^32] in every lane (VALU, not LDS pipe).
__device__ __forceinline__ float fold32(float s, int lane) {
#if defined(__has_builtin) && __has_builtin(__builtin_amdgcn_permlane32_swap)
    int si = __float_as_int(s);
    auto pq = __builtin_amdgcn_permlane32_swap(si, si, false, false);
    return __int_as_float(pq[0]) + __int_as_float(pq[1]);
#else
    return s + __shfl(s, lane ^ 32, 64);
#endif
}

__global__ void __launch_bounds__(1024, 4)
rnn_kernel(const float* __restrict__ x, const float* __restrict__ H,
           const float* __restrict__ U, const float* __restrict__ A,
           const float* __restrict__ bvec, const float* __restrict__ cvec,
           float* __restrict__ out)
{
    // A-frag ping-pong: [buf][kt][lane][idx]; lane = chunk*16 + arow,
    // arow 0-7 = h_hi(batch row arow), 8-15 = h_lo(batch row arow-8).
    __shared__ __align__(16) __bf16 lds_A[2][KT][64][8];       // 14 KB
    // xu ping-pong in reader-lane layout: reader lane L reads [tile][L][0..3]
    __shared__ __align__(16) float  lds_xu[2][NCW][64][4];     // 26 KB
    __shared__ float lds_h[BB][204];                            // final h

    const int tid  = threadIdx.x;
    const int lane = tid & 63;
    const int wv   = tid >> 6;          // wave id 0..15
    const int m    = lane & 15;         // A-row / C-col index within tile
    const int quad = lane >> 4;         // 0..3
    const int b0   = blockIdx.x * BB;

    // zero-init A-frag buffers: h0 = 0; phantom K rows stay 0 forever.
    {
        __bf16* p0 = &lds_A[0][0][0][0];
        for (int i = tid; i < 2*KT*64*8; i += 1024) p0[i] = (__bf16)0.0f;
    }

    const int r8    = m & 7;
    const bool isLo = (m >= 8);
    floatx4 zero4 = {0.0f, 0.0f, 0.0f, 0.0f};

    // ---- compute-wave setup: stationary H fragments + epilogue indices ----
    bf16x8 Bhi[KT], Blo[KT];
    int  jcol = 0, e_ktd = 0, e_rowb = 0, e_idx = 0;
    bool e_wr = false;
    if (wv < NCW) {
        jcol = wv*16 + m;                               // output column (>=198 phantom)
        #pragma unroll
        for (int kt = 0; kt < KT; ++kt) {
            bf16x8 hi8, lo8;
            #pragma unroll
            for (int idx = 0; idx < 8; ++idx) {
                int k = kt*32 + quad*8 + idx;
                float v = (jcol < HID && k < HID) ? H[jcol*HID + k] : 0.0f; // B[k][j]=H[j][k]
                __bf16 h = (__bf16)v;
                hi8[idx] = h;
                lo8[idx] = (__bf16)(v - (float)h);
            }
            Bhi[kt] = hi8; Blo[kt] = lo8;
        }
        e_ktd  = jcol >> 5;
        e_rowb = ((jcol & 31) >> 3)*16 + quad*4;  // + reg gives the A-row slot
        e_idx  = jcol & 7;
        e_wr   = (jcol < HID);
    }

    // ---- xu-producer setup (waves 13,14) ----
    const float* xrow = x + (size_t)(b0 + r8) * IN_DIM + quad*8;
    const size_t tstride = (size_t)BATCH * IN_DIM;
    const int tbase = (wv == 13) ? 0 : 7;
    const int tcnt  = (wv == 13) ? 7 : 6;
    bf16x8 Uhi[7], Ulo[7];
    float  biasv[7];
    if (wv == 13 || wv == 14) {
        #pragma unroll
        for (int q = 0; q < 7; ++q) {
            const int tile = tbase + q;
            const int j = tile*16 + m;
            const bool real = (q < tcnt) && (j < HID);
            biasv[q] = real ? bvec[j] : 0.0f;
            bf16x8 uh, ul;
            #pragma unroll
            for (int idx = 0; idx < 8; ++idx) {
                int i = quad*8 + idx;
                float v = (real && i < IN_DIM) ? U[i*HID + j] : 0.0f;   // B[i][j]=U[i][j]
                __bf16 h = (__bf16)v;
                uh[idx] = h;
                ul[idx] = (__bf16)(v - (float)h);
            }
            Uhi[q] = uh; Ulo[q] = ul;
        }
    }

    // stager body: compute xu[tn] into lds_xu[buf]
    auto stage = [&](int tn, int buf) {
        floatx4 f0 = *(const floatx4*)(xrow + (size_t)tn * tstride);
        floatx4 f1 = (quad < 3) ? *(const floatx4*)(xrow + (size_t)tn * tstride + 4) : zero4;
        float xv[8] = {f0[0],f0[1],f0[2],f0[3], f1[0],f1[1],f1[2],f1[3]};
        bf16x8 ax;
        #pragma unroll
        for (int i = 0; i < 8; ++i) {
            __bf16 h = (__bf16)xv[i];
            ax[i] = isLo ? (__bf16)(xv[i] - (float)h) : h;
        }
        #pragma unroll
        for (int q = 0; q < 7; ++q) {
            if (q < tcnt) {
                floatx4 c1 = mfma16(ax, Uhi[q], zero4);
                floatx4 c2 = mfma16(ax, Ulo[q], zero4);
                floatx4 w;
                #pragma unroll
                for (int reg = 0; reg < 4; ++reg)
                    w[reg] = fold32(c1[reg] + c2[reg], lane) + biasv[q];
                *(floatx4*)&lds_xu[buf][tbase + q][lane][0] = w;
            }
        }
    };

    if (wv == 13 || wv == 14) stage(0, 0);   // prologue: xu[0] ready pre-loop

    // ================= time loop =================
    #pragma unroll 1
    for (int t = 0; t < T_STEPS; ++t) {
        const int rb = t & 1;
        const int wb = rb ^ 1;

        __syncthreads();   // all prior writes into rb / lds_xu[rb] visible

        if (wv < NCW) {
            // xu for this step (independent of MFMAs; issued with A-reads)
            floatx4 xu4 = *(const floatx4*)&lds_xu[rb][wv][lane][0];

            floatx4 aA = zero4, aB = zero4, aC = zero4, aD = zero4;
            #pragma unroll
            for (int kt = 0; kt < KT; ++kt) {
                bf16x8 a;
                if (kt == 6) {
                    a = (bf16x8){};
                    if (quad == 0) a = *(const bf16x8*)&lds_A[rb][6][lane][0];
                } else {
                    a = *(const bf16x8*)&lds_A[rb][kt][lane][0];
                }
                if (kt & 1) { aB = mfma16(a, Bhi[kt], aB); aD = mfma16(a, Blo[kt], aD); }
                else        { aA = mfma16(a, Bhi[kt], aA); aC = mfma16(a, Blo[kt], aC); }
            }

            // fold hi/lo row-halves, add xu+bias, tanh, split, scatter to wb
            #pragma unroll
            for (int reg = 0; reg < 4; ++reg) {
                float s = (aA[reg] + aB[reg]) + (aC[reg] + aD[reg]);
                float v = fast_tanh(fold32(s, lane) + xu4[reg]);
                __bf16 h = (__bf16)v;
                __bf16 wval = (quad < 2) ? h : (__bf16)(v - (float)h);
                if (e_wr) {
                    lds_A[wb][e_ktd][e_rowb + reg][e_idx] = wval;
                    if (t == T_STEPS - 1 && quad < 2) lds_h[quad*4 + reg][jcol] = v;
                }
            }
        } else if (wv == 13 || wv == 14) {
            const int tn = (t + 1 < T_STEPS) ? (t + 1) : t;
            stage(tn, wb);
        }
        // wave 15: barrier only
    }

    __syncthreads();

    // ---- output: out[b][o] = sum_k h[b][k]*A[o][k] + c[o] (tiny, scalar) ----
    if (tid < BB * OUT_DIM) {
        const int r = tid / OUT_DIM;
        const int o = tid % OUT_DIM;
        float s = cvec[o];
        for (int k = 0; k < HID; ++k) s += lds_h[r][k] * A[o*HID + k];
        out[(size_t)(b0 + r) * OUT_DIM + o] = s;
    }
}

extern "C" void kernel_launch(void* const* d_in, const int* in_sizes, int n_in,
                              void* d_out, int out_size, void* d_ws, size_t ws_size,
                              hipStream_t stream) {
    const float* x  = (const float*)d_in[0];
    const float* H  = (const float*)d_in[1];
    const float* U  = (const float*)d_in[2];
    const float* A  = (const float*)d_in[3];
    const float* b  = (const float*)d_in[4];
    const float* c  = (const float*)d_in[5];
    float* out = (float*)d_out;

    rnn_kernel<<<dim3(BATCH / BB), dim3(1024), 0, stream>>>(x, H, U, A, b, c, out);
}

// Round 8
// 451.465 us; speedup vs baseline: 4.4038x; 4.4038x over previous
//
#include <hip/hip_runtime.h>

// SimpleRNN: h_{t+1} = tanh(h_t @ H^T + x_t @ U + b); out = h_T @ A^T + c
// T=512 B=2048 IN=28 HID=198 OUT=10, all fp32.
//
// R8: persistent kernel, grid=256 (1 block/CU), BB=8 batch rows/block,
// 1024 threads = 16 waves = 4 waves/SIMD (R6 lesson: fewer is latency-dead).
// FP16 SINGLE-PASS recurrence (replaces R5's bf16 hi/lo 2-pass emulation):
// fp16 has 11 mantissa bits; error model gives steady-state absmax ~3e-3,
// well under the 3.6e-2 threshold. Halves MFMAs (8/wave/step), halves LDS
// read cycles (A-frag stored 32 unique rows; lanes m and m+8 broadcast-read
// the same address - 2-way same-address is free), removes the permlane fold
// and hi/lo split VALU entirely.
//
// Waves 0-12: compute one 16-col N-tile each (13x16 = 208 >= 198).
// Wave 15: x-stager packs x[t+1] (fp16) into A-slot kt=7; B[7]=U.
// Epilogue: C rows 8-15 duplicate rows 0-7 (A rows deduped), so the 8 real
// rows are covered by all 4 quads with 2 tanh + 2 ds_write_b16 per lane:
//   row = (quad&1)*4 + regsel, regsel = (quad>>1)*2 + e, e in {0,1}.
// One __syncthreads per step. R7 lesson: keep the register-live-range union
// small - stationary frags are 8 half8 = 32 VGPRs total.

#define T_STEPS 512
#define BATCH   2048
#define IN_DIM  28
#define HID     198
#define OUT_DIM 10
#define BB      8    // batch rows per block
#define KT      8    // 7 H k-tiles of 32 (224 >= 198) + 1 U/x slot
#define NCW     13   // compute waves / N-tiles

typedef __attribute__((ext_vector_type(8))) _Float16 half8;
typedef __attribute__((ext_vector_type(4))) float   floatx4;

__device__ __forceinline__ floatx4 mfma16(half8 a, half8 b, floatx4 c) {
    return __builtin_amdgcn_mfma_f32_16x16x32_f16(a, b, c, 0, 0, 0);
}

// tanh(x) = 1 - 2/(exp(2x)+1); exp2-based, saturates via IEEE inf/0.
__device__ __forceinline__ float fast_tanh(float x) {
    float e = __builtin_amdgcn_exp2f(x * 2.885390081777926357f); // exp(2x)
    float r = __builtin_amdgcn_rcpf(e + 1.0f);
    return __builtin_fmaf(-2.0f, r, 1.0f);
}

__global__ void __launch_bounds__(1024, 4)
rnn_kernel(const float* __restrict__ x, const float* __restrict__ H,
           const float* __restrict__ U, const float* __restrict__ A,
           const float* __restrict__ bvec, const float* __restrict__ cvec,
           float* __restrict__ out)
{
    // Dedup A-frag ping-pong: [buf][kt][chunk*8 + r8][idx], fp16.
    // Compute lane (m,quad) reads 16B at [kt][quad*8 + (m&7)] - lanes m and
    // m+8 hit the same address (2-way broadcast, free).
    __shared__ __align__(16) _Float16 lds_A[2][KT][32][8];   // 8 KB
    __shared__ float lds_h[BB][204];                          // final h, fp32

    const int tid  = threadIdx.x;
    const int lane = tid & 63;
    const int wv   = tid >> 6;          // wave id 0..15
    const int m    = lane & 15;         // A-row / C-col index within tile
    const int quad = lane >> 4;         // 0..3
    const int r8   = m & 7;
    const int b0   = blockIdx.x * BB;

    // zero-init both buffers (h0 = 0; phantom K rows stay 0 forever)
    {
        _Float16* p0 = &lds_A[0][0][0][0];
        for (int i = tid; i < 2*KT*32*8; i += 1024) p0[i] = (_Float16)0.0f;
    }
    __syncthreads();   // zero-fill complete before stager prologue writes

    floatx4 zero4 = {0.0f, 0.0f, 0.0f, 0.0f};

    // ---- compute-wave setup: stationary fp16 B fragments (H + U) ----
    half8 Bf[KT];
    float bias_eff = 0.0f;
    int   jcol = 0, e_ktd = 0, e_chunk8 = 0, e_idx = 0;
    bool  e_wr = false;
    if (wv < NCW) {
        jcol = wv*16 + m;                               // output column (>=198 phantom)
        bias_eff = (jcol < HID) ? bvec[jcol] : 0.0f;
        #pragma unroll
        for (int kt = 0; kt < 7; ++kt) {
            half8 f;
            #pragma unroll
            for (int idx = 0; idx < 8; ++idx) {
                int k = kt*32 + quad*8 + idx;
                float v = (jcol < HID && k < HID) ? H[jcol*HID + k] : 0.0f; // B[k][j]=H[j][k]
                f[idx] = (_Float16)v;
            }
            Bf[kt] = f;
        }
        {   // slot 7: U
            half8 f;
            #pragma unroll
            for (int idx = 0; idx < 8; ++idx) {
                int i = quad*8 + idx;
                float v = (jcol < HID && i < IN_DIM) ? U[i*HID + jcol] : 0.0f;
                f[idx] = (_Float16)v;
            }
            Bf[7] = f;
        }
        e_ktd    = jcol >> 5;
        e_chunk8 = ((jcol & 31) >> 3) * 8;
        e_idx    = jcol & 7;
        e_wr     = (jcol < HID);
    }

    // ---- epilogue row split: all 4 quads cover the 8 real C rows ----
    // quad0: regs {0,1} -> rows {0,1}; quad1: regs {0,1} -> rows {4,5};
    // quad2: regs {2,3} -> rows {2,3}; quad3: regs {2,3} -> rows {6,7}.
    const int regbase = (quad >> 1) * 2;            // 0 or 2
    const int rowbase = (quad & 1) * 4 + regbase;   // row = rowbase + e - regbase... see below

    // ---- stager setup (wave 15, lanes 0-31): x A-frag rows ----
    const int srow  = lane & 31;        // chunk*8 + r8
    const int sq    = srow >> 3;        // k-chunk 0..3
    const int sr8   = srow & 7;         // batch row
    const float* xrow_s = x + (size_t)(b0 + sr8) * IN_DIM + sq*8;
    const size_t tstride = (size_t)BATCH * IN_DIM;

    auto stage = [&](int tn, int buf) {
        if (lane < 32) {
            const float* p = xrow_s + (size_t)tn * tstride;
            floatx4 f0 = *(const floatx4*)p;
            floatx4 f1 = (sq < 3) ? *(const floatx4*)(p + 4) : zero4;
            half8 ax;
            ax[0] = (_Float16)f0[0]; ax[1] = (_Float16)f0[1];
            ax[2] = (_Float16)f0[2]; ax[3] = (_Float16)f0[3];
            ax[4] = (_Float16)f1[0]; ax[5] = (_Float16)f1[1];
            ax[6] = (_Float16)f1[2]; ax[7] = (_Float16)f1[3];
            *(half8*)&lds_A[buf][7][srow][0] = ax;
        }
    };

    if (wv == 15) stage(0, 0);   // prologue: x[0] into buf 0

    // ================= time loop =================
    #pragma unroll 1
    for (int t = 0; t < T_STEPS; ++t) {
        const int rb = t & 1;
        const int wb = rb ^ 1;

        __syncthreads();   // prior writes into rb visible; wb free to write

        if (wv < NCW) {
            // 8 MFMAs in 2 chains of 4; bias in chain-0 C-init.
            floatx4 acc1 = (floatx4){bias_eff, bias_eff, bias_eff, bias_eff};
            floatx4 acc2 = zero4;
            #pragma unroll
            for (int kt = 0; kt < KT; ++kt) {
                half8 a = *(const half8*)&lds_A[rb][kt][quad*8 + r8][0];
                if (kt & 1) acc2 = mfma16(a, Bf[kt], acc2);
                else        acc1 = mfma16(a, Bf[kt], acc1);
            }
            // epilogue: 2 tanh + 2 fp16 writes per lane (rows split over quads)
            if (e_wr) {
                #pragma unroll
                for (int e = 0; e < 2; ++e) {
                    const int reg = regbase + e;
                    const int row = (quad & 1) * 4 + reg;   // 0..7, all 8 covered
                    float v = fast_tanh(acc1[reg] + acc2[reg]);
                    lds_A[wb][e_ktd][e_chunk8 + row][e_idx] = (_Float16)v;
                    if (t == T_STEPS - 1) lds_h[row][jcol] = v;
                }
            }
        } else if (wv == 15) {
            const int tn = (t + 1 < T_STEPS) ? (t + 1) : t;
            stage(tn, wb);
        }
        // waves 13,14: barrier only
    }

    __syncthreads();

    // ---- output: out[b][o] = sum_k h[b][k]*A[o][k] + c[o] (tiny, scalar) ----
    if (tid < BB * OUT_DIM) {
        const int r = tid / OUT_DIM;
        const int o = tid % OUT_DIM;
        float s = cvec[o];
        for (int k = 0; k < HID; ++k) s += lds_h[r][k] * A[o*HID + k];
        out[(size_t)(b0 + r) * OUT_DIM + o] = s;
    }
}

extern "C" void kernel_launch(void* const* d_in, const int* in_sizes, int n_in,
                              void* d_out, int out_size, void* d_ws, size_t ws_size,
                              hipStream_t stream) {
    const float* x  = (const float*)d_in[0];
    const float* H  = (const float*)d_in[1];
    const float* U  = (const float*)d_in[2];
    const float* A  = (const float*)d_in[3];
    const float* b  = (const float*)d_in[4];
    const float* c  = (const float*)d_in[5];
    float* out = (float*)d_out;

    rnn_kernel<<<dim3(BATCH / BB), dim3(1024), 0, stream>>>(x, H, U, A, b, c, out);
}